// Round 1
// baseline (460.649 us; speedup 1.0000x reference)
//
#include <hip/hip_runtime.h>
#include <math.h>

#define Bc 8
#define Tc 60
#define Sc 36
#define Hc_ 4
#define Ec 16
#define PEc 16
#define ADc 12
#define TAc 10
#define OUTc 64
#define KEEP 648
#define EPSc 1e-5f

// workspace layout (float offsets)
#define WS_MU     0
#define WS_VAR    64
#define WS_PE     128                      // B*T*PE = 7680
#define WS_BIDIR  7808                     // L*H*S*S = 10368
#define WS_H0     18176                    // B*H*T*S*E = 1105920
#define WS_H1     1124096                  // 1105920
#define WS_ALPHA  2230016                  // B*H*T*S*S = 2488320
#define WS_ADJSUM 4718336                  // B*H*S*S = 41472
#define WS_ADJ    4759808                  // 41472
// total = 4801280 floats ~= 19.2 MB

__device__ __forceinline__ float lrelu(float v){ return v >= 0.f ? v : 0.01f*v; }

// ---------------- kernel 1: BN stats per timestep channel ----------------
__global__ __launch_bounds__(256) void k_bnstats(const float* __restrict__ x, float* __restrict__ ws){
    int t = blockIdx.x;
    int tid = threadIdx.x;
    float s0 = 0.f, s1 = 0.f;
    for (int i = tid; i < Bc*Sc; i += 256){
        int b = i / Sc, s = i % Sc;
        float v = x[(b*Tc + t)*Sc + s];
        s0 += v; s1 += v*v;
    }
    __shared__ float r0[256], r1[256];
    r0[tid] = s0; r1[tid] = s1; __syncthreads();
    for (int off = 128; off; off >>= 1){
        if (tid < off){ r0[tid] += r0[tid+off]; r1[tid] += r1[tid+off]; }
        __syncthreads();
    }
    if (tid == 0){
        float mu = r0[0] / (float)(Bc*Sc);
        float var = r1[0] / (float)(Bc*Sc) - mu*mu;
        ws[WS_MU + t] = mu;
        ws[WS_VAR + t] = var;
    }
}

// ------------- kernel 2: embedding h0, positional encoding, bidir -------------
__global__ __launch_bounds__(256) void k_embed(const float* __restrict__ x,
                        const float* __restrict__ times,
                        const float* __restrict__ mask,
                        const float* __restrict__ bn_g,
                        const float* __restrict__ bn_b,
                        const float* __restrict__ obs_w,
                        const float* __restrict__ bidw,
                        float* __restrict__ ws){
    int gid = blockIdx.x * 256 + threadIdx.x;
    // positional encoding (B*T*8 sin/cos pairs)
    if (gid < Bc*Tc*8){
        int b = gid / (Tc*8); int r = gid % (Tc*8); int t = r / 8; int j = r % 8;
        float div = expf(-(float)j * 1.15129254649702284f);   // log(10000)/8
        float ang = times[b*Tc + t] * div;
        float* pe = ws + WS_PE + (b*Tc + t)*PEc;
        pe[2*j]   = sinf(ang);
        pe[2*j+1] = cosf(ang);
    }
    // bidir matrices for both layers: lrelu(bw[h,s,:] . bw[h,j,:])
    if (gid < 2*Hc_*Sc*Sc){
        int lay = gid / (Hc_*Sc*Sc); int r = gid % (Hc_*Sc*Sc);
        int h = r / (Sc*Sc); int sj = r % (Sc*Sc); int s = sj / Sc; int j = sj % Sc;
        const float* ps = bidw + ((lay*Hc_ + h)*Sc + s)*ADc;
        const float* pj = bidw + ((lay*Hc_ + h)*Sc + j)*ADc;
        float acc = 0.f;
        for (int d = 0; d < ADc; d++) acc += ps[d]*pj[d];
        ws[WS_BIDIR + gid] = lrelu(acc);
    }
    // h0[b,h,t,s,e] = lrelu(xn[b,t,s] * obs_w[s, h*16+e]) * mask[b,t,s]
    const int N = Bc*Hc_*Tc*Sc*Ec;
    if (gid < N){
        int e = gid % Ec;
        int s = (gid / Ec) % Sc;
        int t = (gid / (Ec*Sc)) % Tc;
        int h = (gid / (Ec*Sc*Tc)) % Hc_;
        int b =  gid / (Ec*Sc*Tc*Hc_);
        float mu = ws[WS_MU + t], var = ws[WS_VAR + t];
        float xv = x[(b*Tc + t)*Sc + s];
        float xn = (xv - mu) * rsqrtf(var + EPSc) * bn_g[t] + bn_b[t];
        float hv = lrelu(xn * obs_w[s*64 + h*Ec + e]) * mask[(b*Tc + t)*Sc + s];
        ws[WS_H0 + gid] = hv;
    }
}

// ---------- kernel 3: layer 0 fully fused (alpha -> w -> message pass) ----------
__global__ __launch_bounds__(256) void k_layer0(const float* __restrict__ attn,
                         const float* __restrict__ projW,
                         const float* __restrict__ projb,
                         float* __restrict__ ws){
    int idx = blockIdx.x;                 // (b*H + h)*T + t
    int t = idx % Tc; int bh = idx / Tc; int h = bh % Hc_; int b = bh / Hc_;
    int tid = threadIdx.x;
    __shared__ float sh_h[Sc*Ec];         // 576
    __shared__ float sh_pe[PEc];
    __shared__ float sh_at[Sc*ADc];       // 432
    __shared__ float sh_hp[Sc*28];        // 1008
    __shared__ float sh_w[Sc*Sc];         // 1296
    const float* hsrc = ws + WS_H0 + (size_t)idx*Sc*Ec;
    float*       hdst = ws + WS_H1 + (size_t)idx*Sc*Ec;
    for (int i = tid; i < Sc*Ec; i += 256) sh_h[i] = hsrc[i];
    for (int i = tid; i < PEc;   i += 256) sh_pe[i] = ws[WS_PE + (b*Tc + t)*PEc + i];
    for (int i = tid; i < Sc*ADc;i += 256) sh_at[i] = attn[h*Sc*ADc + i];   // lay 0
    __syncthreads();
    for (int i = tid; i < Sc*28; i += 256){
        int s = i / 28, d = i % 28;
        float acc = projb[d];
        const float* w = projW + d*Ec;
        const float* hh = sh_h + s*Ec;
        for (int e = 0; e < Ec; e++) acc += hh[e]*w[e];
        sh_hp[i] = acc;
    }
    __syncthreads();
    const float* bid = ws + WS_BIDIR + h*Sc*Sc;  // lay 0
    for (int i = tid; i < Sc*Sc; i += 256){
        int s = i / Sc, j = i % Sc;
        const float* hp = sh_hp + s*28;
        float acc = 0.f;
        for (int d = 0; d < ADc; d++) acc += hp[d]*sh_at[j*ADc + d];
        for (int d = 0; d < PEc; d++) acc += hp[ADc + d]*sh_pe[d];
        float alpha = lrelu(acc);
        sh_w[i] = lrelu(bid[i]*alpha);     // adj == 1 at layer 0
    }
    __syncthreads();
    for (int i = tid; i < Sc*Ec; i += 256){
        int s = i / Ec, e = i % Ec;
        float acc = 0.f;
        for (int j = 0; j < Sc; j++) acc += lrelu(sh_h[j*Ec + e]*sh_w[s*Sc + j]);
        hdst[i] = lrelu(acc);
    }
}

// ---------------- kernel 4: layer 1 alpha (materialized) ----------------
__global__ __launch_bounds__(256) void k_alpha1(const float* __restrict__ attn,
                         const float* __restrict__ projW,
                         const float* __restrict__ projb,
                         float* __restrict__ ws){
    int idx = blockIdx.x;
    int t = idx % Tc; int bh = idx / Tc; int h = bh % Hc_; int b = bh / Hc_;
    int tid = threadIdx.x;
    __shared__ float sh_h[Sc*Ec];
    __shared__ float sh_pe[PEc];
    __shared__ float sh_at[Sc*ADc];
    __shared__ float sh_hp[Sc*28];
    const float* hsrc = ws + WS_H1 + (size_t)idx*Sc*Ec;
    float*       adst = ws + WS_ALPHA + (size_t)idx*Sc*Sc;
    for (int i = tid; i < Sc*Ec; i += 256) sh_h[i] = hsrc[i];
    for (int i = tid; i < PEc;   i += 256) sh_pe[i] = ws[WS_PE + (b*Tc + t)*PEc + i];
    for (int i = tid; i < Sc*ADc;i += 256) sh_at[i] = attn[(Hc_ + h)*Sc*ADc + i];  // lay 1
    __syncthreads();
    for (int i = tid; i < Sc*28; i += 256){
        int s = i / 28, d = i % 28;
        float acc = projb[d];
        const float* w = projW + d*Ec;
        const float* hh = sh_h + s*Ec;
        for (int e = 0; e < Ec; e++) acc += hh[e]*w[e];
        sh_hp[i] = acc;
    }
    __syncthreads();
    for (int i = tid; i < Sc*Sc; i += 256){
        int s = i / Sc, j = i % Sc;
        const float* hp = sh_hp + s*28;
        float acc = 0.f;
        for (int d = 0; d < ADc; d++) acc += hp[d]*sh_at[j*ADc + d];
        for (int d = 0; d < PEc; d++) acc += hp[ADc + d]*sh_pe[d];
        adst[i] = lrelu(acc);
    }
}

// ---------------- kernel 5: adj column-sum over t (deterministic) ----------------
__global__ __launch_bounds__(256) void k_adjsum(float* __restrict__ ws){
    int gid = blockIdx.x * 256 + threadIdx.x;
    if (gid >= Bc*Hc_*Sc*Sc) return;
    int bh = gid / (Sc*Sc); int sj = gid % (Sc*Sc);
    const float* a = ws + WS_ALPHA + (size_t)bh*Tc*Sc*Sc + sj;
    float acc = 0.f;
    for (int t = 0; t < Tc; t++) acc += a[(size_t)t*Sc*Sc];
    ws[WS_ADJSUM + gid] = acc;
}

// ---------------- kernel 6: adj = lrelu(sum/cnt); prune by stable rank ----------------
__global__ __launch_bounds__(256) void k_prune(const float* __restrict__ mask, float* __restrict__ ws){
    int bh = blockIdx.x; int b = bh / Hc_;
    int tid = threadIdx.x;
    __shared__ float sh_v[Sc*Sc];
    __shared__ float sh_cnt[Sc];
    if (tid < Sc){
        float c = 0.f;
        for (int t = 0; t < Tc; t++) c += mask[(b*Tc + t)*Sc + tid];
        sh_cnt[tid] = c;
    }
    __syncthreads();
    for (int i = tid; i < Sc*Sc; i += 256){
        int s = i / Sc;
        sh_v[i] = lrelu(ws[WS_ADJSUM + bh*Sc*Sc + i] / sh_cnt[s]);
    }
    __syncthreads();
    for (int i = tid; i < Sc*Sc; i += 256){
        float v = sh_v[i];
        int rank = 0;
        for (int k = 0; k < Sc*Sc; k++){
            float u = sh_v[k];
            rank += (u < v) || (u == v && k < i);   // stable-sort rank
        }
        ws[WS_ADJ + bh*Sc*Sc + i] = (rank >= KEEP) ? v : 0.f;
    }
}

// ---------------- kernel 7: pair_sim(adj) -> d_out[18432] ----------------
__global__ __launch_bounds__(256) void k_sim(const float* __restrict__ ws, float* __restrict__ out){
    int tid = threadIdx.x;
    float sq = 0.f, t2 = 0.f;
    for (int i = tid; i < Hc_*Sc*Sc; i += 256){
        float tot = 0.f;
        for (int b = 0; b < Bc; b++){
            float v = ws[WS_ADJ + b*Hc_*Sc*Sc + i];
            sq += v*v; tot += v;
        }
        t2 += tot*tot;
    }
    __shared__ float r0[256], r1[256];
    r0[tid] = sq; r1[tid] = t2; __syncthreads();
    for (int off = 128; off; off >>= 1){
        if (tid < off){ r0[tid] += r0[tid+off]; r1[tid] += r1[tid+off]; }
        __syncthreads();
    }
    if (tid == 0)
        out[Bc*Sc*OUTc] = ((float)Bc*r0[0] - r1[0]) / 49.f / 1296.f;
}

// ---------------- kernel 8: layer 1 message passing ----------------
__global__ __launch_bounds__(256) void k_layer1mp(float* __restrict__ ws){
    int idx = blockIdx.x;
    int bh = idx / Tc; int h = bh % Hc_;
    int tid = threadIdx.x;
    __shared__ float sh_h[Sc*Ec];
    __shared__ float sh_w[Sc*Sc];
    const float* hsrc = ws + WS_H1 + (size_t)idx*Sc*Ec;
    float*       hdst = ws + WS_H0 + (size_t)idx*Sc*Ec;   // h2 reuses h0 buffer
    const float* al  = ws + WS_ALPHA + (size_t)idx*Sc*Sc;
    const float* adj = ws + WS_ADJ + bh*Sc*Sc;
    const float* bid = ws + WS_BIDIR + (Hc_ + h)*Sc*Sc;   // lay 1
    for (int i = tid; i < Sc*Ec; i += 256) sh_h[i] = hsrc[i];
    for (int i = tid; i < Sc*Sc; i += 256) sh_w[i] = lrelu(bid[i]*al[i]*adj[i]);
    __syncthreads();
    for (int i = tid; i < Sc*Ec; i += 256){
        int s = i / Ec, e = i % Ec;
        float acc = 0.f;
        for (int j = 0; j < Sc; j++) acc += lrelu(sh_h[j*Ec + e]*sh_w[s*Sc + j]);
        hdst[i] = lrelu(acc);
    }
}

// ---------------- kernel 9: temporal attention + LNs + output ----------------
__global__ __launch_bounds__(256) void k_final(const float* __restrict__ Wq, const float* __restrict__ bq,
                        const float* __restrict__ Wk, const float* __restrict__ bk,
                        const float* __restrict__ Ws_, const float* __restrict__ bs_,
                        const float* __restrict__ lnt_g, const float* __restrict__ lnt_b,
                        const float* __restrict__ Wse, const float* __restrict__ bse,
                        const float* __restrict__ lns_g, const float* __restrict__ lns_b,
                        const float* __restrict__ ws, float* __restrict__ out){
    int bh = blockIdx.x; int h = bh % Hc_; int b = bh / Hc_;
    int tid = threadIdx.x;
    __shared__ float sh_Kw[Sc*TAc];     // 360
    __shared__ float sh_beta[Sc*Tc];    // 2160
    __shared__ float sh_o1[Sc*32];      // 1152
    __shared__ float sh_o2[Sc*16];      // 576
    __shared__ float r0[256], r1[256];
    const float* h2 = ws + WS_H0;
    const float* pe = ws + WS_PE;
    #define HCV(s,t,d) ((d) < Ec ? h2[((size_t)(bh)*Tc + (t))*Sc*Ec + (s)*Ec + (d)] \
                                 : pe[((b)*Tc + (t))*PEc + (d) - Ec])
    // Kw[s,d] = sum_u (Hc[s,u,:].Wk[d,:] + bk[d]) * Ws[u]
    for (int i = tid; i < Sc*TAc; i += 256){
        int s = i / TAc, d = i % TAc;
        float acc = 0.f;
        for (int t = 0; t < Tc; t++){
            float kv = bk[d];
            for (int q = 0; q < 32; q++) kv += HCV(s, t, q)*Wk[d*32 + q];
            acc += kv*Ws_[t];
        }
        sh_Kw[i] = acc;
    }
    __syncthreads();
    // beta2[s,t] = sum_d (Hc[s,t,:].Wq[d,:] + bq[d]) * Kw[s,d] + bs
    for (int i = tid; i < Sc*Tc; i += 256){
        int s = i / Tc, t = i % Tc;
        float acc = bs_[0];
        for (int d = 0; d < TAc; d++){
            float qv = bq[d];
            for (int q = 0; q < 32; q++) qv += HCV(s, t, q)*Wq[d*32 + q];
            acc += qv*sh_Kw[s*TAc + d];
        }
        sh_beta[i] = acc;
    }
    __syncthreads();
    // LayerNorm over (S,T)
    float s0 = 0.f, s1 = 0.f;
    for (int i = tid; i < Sc*Tc; i += 256){ float v = sh_beta[i]; s0 += v; s1 += v*v; }
    r0[tid] = s0; r1[tid] = s1; __syncthreads();
    for (int off = 128; off; off >>= 1){
        if (tid < off){ r0[tid] += r0[tid+off]; r1[tid] += r1[tid+off]; }
        __syncthreads();
    }
    float m = r0[0] / (float)(Sc*Tc);
    float var = r1[0] / (float)(Sc*Tc) - m*m;
    float inv = rsqrtf(var + EPSc);
    __syncthreads();
    for (int i = tid; i < Sc*Tc; i += 256){
        int s = i / Tc, t = i % Tc;
        sh_beta[i] = (sh_beta[i] - m)*inv*lnt_g[s*Tc + t] + lnt_b[s*Tc + t];
    }
    __syncthreads();
    // out1[s,d] = lrelu(sum_t betaN[s,t]*Hc[s,t,d])
    for (int i = tid; i < Sc*32; i += 256){
        int s = i / 32, d = i % 32;
        float acc = 0.f;
        for (int t = 0; t < Tc; t++) acc += sh_beta[s*Tc + t]*HCV(s, t, d);
        sh_o1[i] = lrelu(acc);
    }
    __syncthreads();
    // out2[s,k] = lrelu(out1[s,:].Wse[k,:] + bse[k])
    for (int i = tid; i < Sc*16; i += 256){
        int s = i / 16, k = i % 16;
        float acc = bse[k];
        for (int d = 0; d < 32; d++) acc += sh_o1[s*32 + d]*Wse[k*32 + d];
        sh_o2[i] = lrelu(acc);
    }
    __syncthreads();
    // LayerNorm over (S,16) + final write
    s0 = 0.f; s1 = 0.f;
    for (int i = tid; i < Sc*16; i += 256){ float v = sh_o2[i]; s0 += v; s1 += v*v; }
    r0[tid] = s0; r1[tid] = s1; __syncthreads();
    for (int off = 128; off; off >>= 1){
        if (tid < off){ r0[tid] += r0[tid+off]; r1[tid] += r1[tid+off]; }
        __syncthreads();
    }
    float m2 = r0[0] / (float)(Sc*16);
    float v2 = r1[0] / (float)(Sc*16) - m2*m2;
    float inv2 = rsqrtf(v2 + EPSc);
    for (int i = tid; i < Sc*16; i += 256){
        int s = i / 16, k = i % 16;
        out[(b*Sc + s)*OUTc + h*16 + k] = (sh_o2[i] - m2)*inv2*lns_g[s*16 + k] + lns_b[s*16 + k];
    }
    #undef HCV
}

extern "C" void kernel_launch(void* const* d_in, const int* in_sizes, int n_in,
                              void* d_out, int out_size, void* d_ws, size_t ws_size,
                              hipStream_t stream){
    const float* x     = (const float*)d_in[0];
    const float* times = (const float*)d_in[1];
    const float* mask  = (const float*)d_in[2];
    const float* bn_g  = (const float*)d_in[3];
    const float* bn_b  = (const float*)d_in[4];
    const float* obs   = (const float*)d_in[5];
    const float* attn  = (const float*)d_in[6];
    const float* bidw  = (const float*)d_in[7];
    const float* projW = (const float*)d_in[8];
    const float* projb = (const float*)d_in[9];
    const float* Wq    = (const float*)d_in[10];
    const float* bq    = (const float*)d_in[11];
    const float* Wk    = (const float*)d_in[12];
    const float* bk    = (const float*)d_in[13];
    const float* Ws_   = (const float*)d_in[14];
    const float* bs_   = (const float*)d_in[15];
    const float* lnt_g = (const float*)d_in[16];
    const float* lnt_b = (const float*)d_in[17];
    const float* Wse   = (const float*)d_in[18];
    const float* bse   = (const float*)d_in[19];
    const float* lns_g = (const float*)d_in[20];
    const float* lns_b = (const float*)d_in[21];
    float* ws  = (float*)d_ws;
    float* out = (float*)d_out;

    k_bnstats<<<Tc, 256, 0, stream>>>(x, ws);
    const int N = Bc*Hc_*Tc*Sc*Ec;
    k_embed<<<(N + 255)/256, 256, 0, stream>>>(x, times, mask, bn_g, bn_b, obs, bidw, ws);
    k_layer0<<<Bc*Hc_*Tc, 256, 0, stream>>>(attn, projW, projb, ws);
    k_alpha1<<<Bc*Hc_*Tc, 256, 0, stream>>>(attn, projW, projb, ws);
    k_adjsum<<<(Bc*Hc_*Sc*Sc + 255)/256, 256, 0, stream>>>(ws);
    k_prune<<<Bc*Hc_, 256, 0, stream>>>(mask, ws);
    k_sim<<<1, 256, 0, stream>>>(ws, out);
    k_layer1mp<<<Bc*Hc_*Tc, 256, 0, stream>>>(ws);
    k_final<<<Bc*Hc_, 256, 0, stream>>>(Wq, bq, Wk, bk, Ws_, bs_, lnt_g, lnt_b,
                                        Wse, bse, lns_g, lns_b, ws, out);
}

// Round 2
// 285.663 us; speedup vs baseline: 1.6126x; 1.6126x over previous
//
#include <hip/hip_runtime.h>
#include <math.h>

#define Bc 8
#define Tc 60
#define Sc 36
#define Hc_ 4
#define Ec 16
#define PEc 16
#define ADc 12
#define TAc 10
#define OUTc 64
#define KEEP 648
#define EPSc 1e-5f

// workspace layout (float offsets)
#define WS_MU     0
#define WS_VAR    64
#define WS_PE     128                      // B*T*PE = 7680
#define WS_BIDIR  7808                     // L*H*S*S = 10368
#define WS_H2     18176                    // B*H*T*S*E = 1105920  (layer-1 output)
#define WS_H1     1124096                  // 1105920              (layer-0 output)
#define WS_ALPHA  2230016                  // B*H*T*S*S = 2488320
#define WS_ADJSUM 4718336                  // B*H*S*S = 41472
#define WS_ADJ    4759808                  // 41472

__device__ __forceinline__ float lrelu(float v){ return v >= 0.f ? v : 0.01f*v; }

// ------------- kernel 1: BN stats per t + positional encoding + bidir -------------
__global__ __launch_bounds__(256) void k_pre(const float* __restrict__ x,
                      const float* __restrict__ times,
                      const float* __restrict__ bidw,
                      float* __restrict__ ws){
    int tid = threadIdx.x;
    __shared__ float r0[256], r1[256];
    if (blockIdx.x < Tc){
        int t = blockIdx.x;
        float s0 = 0.f, s1 = 0.f;
        for (int i = tid; i < Bc*Sc; i += 256){
            int b = i / Sc, s = i % Sc;
            float v = x[(b*Tc + t)*Sc + s];
            s0 += v; s1 += v*v;
        }
        r0[tid] = s0; r1[tid] = s1; __syncthreads();
        for (int off = 128; off; off >>= 1){
            if (tid < off){ r0[tid] += r0[tid+off]; r1[tid] += r1[tid+off]; }
            __syncthreads();
        }
        if (tid == 0){
            float mu = r0[0] / (float)(Bc*Sc);
            ws[WS_MU + t] = mu;
            ws[WS_VAR + t] = r1[0] / (float)(Bc*Sc) - mu*mu;
        }
    }
    int gid = blockIdx.x * 256 + tid;
    if (gid < Bc*Tc*8){
        int b = gid / (Tc*8); int r = gid % (Tc*8); int t = r / 8; int j = r % 8;
        float div = expf(-(float)j * 1.15129254649702284f);   // log(10000)/8
        float ang = times[b*Tc + t] * div;
        float* pe = ws + WS_PE + (b*Tc + t)*PEc;
        pe[2*j]   = sinf(ang);
        pe[2*j+1] = cosf(ang);
    }
    if (gid < 2*Hc_*Sc*Sc){
        int r = gid; int lay = r / (Hc_*Sc*Sc); r %= (Hc_*Sc*Sc);
        int h = r / (Sc*Sc); int sj = r % (Sc*Sc); int s = sj / Sc; int j = sj % Sc;
        const float* ps = bidw + ((lay*Hc_ + h)*Sc + s)*ADc;
        const float* pj = bidw + ((lay*Hc_ + h)*Sc + j)*ADc;
        float acc = 0.f;
        #pragma unroll
        for (int d = 0; d < ADc; d++) acc += ps[d]*pj[d];
        ws[WS_BIDIR + gid] = lrelu(acc);
    }
}

// ---- kernel 2: fused BN-apply + embed + layer0 (alpha0,w0,mp -> h1) + alpha1 ----
__global__ __launch_bounds__(256) void k_layer01(const float* __restrict__ x,
                          const float* __restrict__ mask,
                          const float* __restrict__ bn_g,
                          const float* __restrict__ bn_b,
                          const float* __restrict__ obs_w,
                          const float* __restrict__ attn,
                          const float* __restrict__ projW,
                          const float* __restrict__ projb,
                          float* __restrict__ ws){
    int idx = blockIdx.x;                 // (b*H + h)*T + t
    int t = idx % Tc; int bh = idx / Tc; int h = bh % Hc_; int b = bh / Hc_;
    int tid = threadIdx.x;
    __shared__ float sh_h[Sc*Ec];         // h0
    __shared__ float sh_h1[Sc*Ec];
    __shared__ float sh_pe[PEc];
    __shared__ float sh_at0[Sc*ADc];
    __shared__ float sh_at1[Sc*ADc];
    __shared__ float sh_hp[Sc*28];
    __shared__ float sh_w[Sc*Sc];
    __shared__ float sh_xn[Sc];
    __shared__ float sh_m[Sc];
    if (tid < Sc){
        float mu = ws[WS_MU + t], var = ws[WS_VAR + t];
        float xv = x[(b*Tc + t)*Sc + tid];
        sh_xn[tid] = (xv - mu) * rsqrtf(var + EPSc) * bn_g[t] + bn_b[t];
        sh_m[tid]  = mask[(b*Tc + t)*Sc + tid];
    }
    for (int i = tid; i < PEc; i += 256) sh_pe[i] = ws[WS_PE + (b*Tc + t)*PEc + i];
    for (int i = tid; i < Sc*ADc; i += 256){
        sh_at0[i] = attn[h*Sc*ADc + i];
        sh_at1[i] = attn[(Hc_ + h)*Sc*ADc + i];
    }
    __syncthreads();
    for (int i = tid; i < Sc*Ec; i += 256){
        int s = i / Ec, e = i % Ec;
        sh_h[i] = lrelu(sh_xn[s]*obs_w[s*64 + h*Ec + e]) * sh_m[s];
    }
    __syncthreads();
    // hp0 = h0 @ projW.T + projb
    for (int i = tid; i < Sc*28; i += 256){
        int s = i / 28, d = i % 28;
        float acc = projb[d];
        const float* w = projW + d*Ec;
        const float* hh = sh_h + s*Ec;
        #pragma unroll
        for (int e = 0; e < Ec; e++) acc += hh[e]*w[e];
        sh_hp[i] = acc;
    }
    __syncthreads();
    const float* bid0 = ws + WS_BIDIR + h*Sc*Sc;
    for (int i = tid; i < Sc*Sc; i += 256){
        int s = i / Sc, j = i % Sc;
        const float* hp = sh_hp + s*28;
        float acc = 0.f;
        #pragma unroll
        for (int d = 0; d < ADc; d++) acc += hp[d]*sh_at0[j*ADc + d];
        #pragma unroll
        for (int d = 0; d < PEc; d++) acc += hp[ADc + d]*sh_pe[d];
        sh_w[i] = lrelu(bid0[i]*lrelu(acc));     // adj == 1 at layer 0
    }
    __syncthreads();
    float* h1g = ws + WS_H1 + (size_t)idx*Sc*Ec;
    for (int i = tid; i < Sc*Ec; i += 256){
        int s = i / Ec, e = i % Ec;
        float acc = 0.f;
        #pragma unroll 6
        for (int j = 0; j < Sc; j++) acc += lrelu(sh_h[j*Ec + e]*sh_w[s*Sc + j]);
        float v = lrelu(acc);
        sh_h1[i] = v;
        h1g[i] = v;
    }
    __syncthreads();
    // hp1 = h1 @ projW.T + projb  (reuse sh_hp)
    for (int i = tid; i < Sc*28; i += 256){
        int s = i / 28, d = i % 28;
        float acc = projb[d];
        const float* w = projW + d*Ec;
        const float* hh = sh_h1 + s*Ec;
        #pragma unroll
        for (int e = 0; e < Ec; e++) acc += hh[e]*w[e];
        sh_hp[i] = acc;
    }
    __syncthreads();
    float* adst = ws + WS_ALPHA + (size_t)idx*Sc*Sc;
    for (int i = tid; i < Sc*Sc; i += 256){
        int s = i / Sc, j = i % Sc;
        const float* hp = sh_hp + s*28;
        float acc = 0.f;
        #pragma unroll
        for (int d = 0; d < ADc; d++) acc += hp[d]*sh_at1[j*ADc + d];
        #pragma unroll
        for (int d = 0; d < PEc; d++) acc += hp[ADc + d]*sh_pe[d];
        adst[i] = lrelu(acc);
    }
}

// ---------------- kernel 3: adj column-sum over t (deterministic) ----------------
__global__ __launch_bounds__(256) void k_adjsum(float* __restrict__ ws){
    int gid = blockIdx.x * 256 + threadIdx.x;
    if (gid >= Bc*Hc_*Sc*Sc) return;
    int bh = gid / (Sc*Sc); int sj = gid % (Sc*Sc);
    const float* a = ws + WS_ALPHA + (size_t)bh*Tc*Sc*Sc + sj;
    float acc = 0.f;
    #pragma unroll 4
    for (int t = 0; t < Tc; t++) acc += a[(size_t)t*Sc*Sc];
    ws[WS_ADJSUM + gid] = acc;
}

// -------- kernel 4: adj = lrelu(sum/cnt); prune by stable rank (1 elem/thread) --------
__global__ __launch_bounds__(256) void k_prune(const float* __restrict__ mask, float* __restrict__ ws){
    int bh = blockIdx.x / 6; int chunk = blockIdx.x % 6;
    int b = bh / Hc_;
    int tid = threadIdx.x;
    __shared__ float sh_v[Sc*Sc];
    __shared__ float sh_cnt[Sc];
    if (tid < Sc){
        float c = 0.f;
        #pragma unroll 4
        for (int t = 0; t < Tc; t++) c += mask[(b*Tc + t)*Sc + tid];
        sh_cnt[tid] = c;
    }
    __syncthreads();
    for (int i = tid; i < Sc*Sc; i += 256){
        int s = i / Sc;
        sh_v[i] = lrelu(ws[WS_ADJSUM + bh*Sc*Sc + i] / sh_cnt[s]);
    }
    __syncthreads();
    int i = chunk*216 + tid;         // 6*216 = 1296
    if (tid < 216){
        float v = sh_v[i];
        int rank = 0;
        #pragma unroll 8
        for (int k = 0; k < Sc*Sc; k++){
            float u = sh_v[k];
            rank += (u < v) || (u == v && k < i);   // stable-sort rank
        }
        ws[WS_ADJ + bh*Sc*Sc + i] = (rank >= KEEP) ? v : 0.f;
    }
}

// ---------------- kernel 5: pair_sim(adj) -> d_out[18432] ----------------
__global__ __launch_bounds__(256) void k_sim(const float* __restrict__ ws, float* __restrict__ out){
    int tid = threadIdx.x;
    float sq = 0.f, t2 = 0.f;
    for (int i = tid; i < Hc_*Sc*Sc; i += 256){
        float tot = 0.f;
        #pragma unroll
        for (int b = 0; b < Bc; b++){
            float v = ws[WS_ADJ + b*Hc_*Sc*Sc + i];
            sq += v*v; tot += v;
        }
        t2 += tot*tot;
    }
    __shared__ float r0[256], r1[256];
    r0[tid] = sq; r1[tid] = t2; __syncthreads();
    for (int off = 128; off; off >>= 1){
        if (tid < off){ r0[tid] += r0[tid+off]; r1[tid] += r1[tid+off]; }
        __syncthreads();
    }
    if (tid == 0)
        out[Bc*Sc*OUTc] = ((float)Bc*r0[0] - r1[0]) / 49.f / 1296.f;
}

// ---------------- kernel 6: layer 1 message passing ----------------
__global__ __launch_bounds__(256) void k_layer1mp(float* __restrict__ ws){
    int idx = blockIdx.x;
    int bh = idx / Tc; int h = bh % Hc_;
    int tid = threadIdx.x;
    __shared__ float sh_h[Sc*Ec];
    __shared__ float sh_w[Sc*Sc];
    const float* hsrc = ws + WS_H1 + (size_t)idx*Sc*Ec;
    float*       hdst = ws + WS_H2 + (size_t)idx*Sc*Ec;
    const float* al  = ws + WS_ALPHA + (size_t)idx*Sc*Sc;
    const float* adj = ws + WS_ADJ + bh*Sc*Sc;
    const float* bid = ws + WS_BIDIR + (Hc_ + h)*Sc*Sc;
    for (int i = tid; i < Sc*Ec; i += 256) sh_h[i] = hsrc[i];
    for (int i = tid; i < Sc*Sc; i += 256) sh_w[i] = lrelu(bid[i]*al[i]*adj[i]);
    __syncthreads();
    for (int i = tid; i < Sc*Ec; i += 256){
        int s = i / Ec, e = i % Ec;
        float acc = 0.f;
        #pragma unroll 6
        for (int j = 0; j < Sc; j++) acc += lrelu(sh_h[j*Ec + e]*sh_w[s*Sc + j]);
        hdst[i] = lrelu(acc);
    }
}

// ---------------- kernel 7: temporal attention + LNs + output ----------------
__global__ __launch_bounds__(256) void k_final(const float* __restrict__ Wq, const float* __restrict__ bq,
                        const float* __restrict__ Wk, const float* __restrict__ bk,
                        const float* __restrict__ Ws_, const float* __restrict__ bs_,
                        const float* __restrict__ lnt_g, const float* __restrict__ lnt_b,
                        const float* __restrict__ Wse, const float* __restrict__ bse,
                        const float* __restrict__ lns_g, const float* __restrict__ lns_b,
                        const float* __restrict__ ws, float* __restrict__ out){
    int bh = blockIdx.x; int h = bh % Hc_; int b = bh / Hc_;
    int tid = threadIdx.x;
    __shared__ float sh_pe[Tc*PEc];     // 960
    __shared__ float sh_Wq[TAc*32];     // 320
    __shared__ float sh_Wk[TAc*32];     // 320
    __shared__ float sh_bq[TAc], sh_bk[TAc];
    __shared__ float sh_ws[Tc];
    __shared__ float sh_Kw[Sc*TAc];     // 360
    __shared__ float sh_beta[Sc*Tc];    // 2160
    __shared__ float sh_o1[Sc*32];      // 1152
    __shared__ float sh_o2[Sc*16];      // 576
    __shared__ float r0[256], r1[256];
    const float* h2 = ws + WS_H2 + (size_t)bh*Tc*Sc*Ec;   // [t][s][e]
    for (int i = tid; i < Tc*PEc; i += 256) sh_pe[i] = ws[WS_PE + b*Tc*PEc + i];
    for (int i = tid; i < TAc*32; i += 256){ sh_Wq[i] = Wq[i]; sh_Wk[i] = Wk[i]; }
    if (tid < TAc){ sh_bq[tid] = bq[tid]; sh_bk[tid] = bk[tid]; }
    if (tid < Tc) sh_ws[tid] = Ws_[tid];
    __syncthreads();
    // Kw[s,d] = sum_t (Hc[s,t,:].Wk[d,:] + bk[d]) * Ws[t]
    for (int i = tid; i < Sc*TAc; i += 256){
        int s = i / TAc, d = i % TAc;
        const float* wk = sh_Wk + d*32;
        float acc = 0.f;
        for (int t = 0; t < Tc; t++){
            const float4* row = (const float4*)(h2 + (t*Sc + s)*Ec);
            float4 a0 = row[0], a1 = row[1], a2 = row[2], a3 = row[3];
            const float* pr = sh_pe + t*PEc;
            float kv = sh_bk[d];
            kv += a0.x*wk[0] + a0.y*wk[1] + a0.z*wk[2] + a0.w*wk[3];
            kv += a1.x*wk[4] + a1.y*wk[5] + a1.z*wk[6] + a1.w*wk[7];
            kv += a2.x*wk[8] + a2.y*wk[9] + a2.z*wk[10] + a2.w*wk[11];
            kv += a3.x*wk[12] + a3.y*wk[13] + a3.z*wk[14] + a3.w*wk[15];
            #pragma unroll
            for (int q = 0; q < PEc; q++) kv += pr[q]*wk[16+q];
            acc += kv*sh_ws[t];
        }
        sh_Kw[i] = acc;
    }
    __syncthreads();
    // beta2[s,t] = sum_d (Hc[s,t,:].Wq[d,:] + bq[d]) * Kw[s,d] + bs
    float bsv = bs_[0];
    for (int i = tid; i < Sc*Tc; i += 256){
        int s = i / Tc, t = i % Tc;
        float r[32];
        const float4* row = (const float4*)(h2 + (t*Sc + s)*Ec);
        float4 a0 = row[0], a1 = row[1], a2 = row[2], a3 = row[3];
        r[0]=a0.x; r[1]=a0.y; r[2]=a0.z; r[3]=a0.w;
        r[4]=a1.x; r[5]=a1.y; r[6]=a1.z; r[7]=a1.w;
        r[8]=a2.x; r[9]=a2.y; r[10]=a2.z; r[11]=a2.w;
        r[12]=a3.x; r[13]=a3.y; r[14]=a3.z; r[15]=a3.w;
        #pragma unroll
        for (int q = 0; q < PEc; q++) r[16+q] = sh_pe[t*PEc + q];
        float acc = bsv;
        #pragma unroll
        for (int d = 0; d < TAc; d++){
            float qv = sh_bq[d];
            const float* wq = sh_Wq + d*32;
            #pragma unroll
            for (int q = 0; q < 32; q++) qv += r[q]*wq[q];
            acc += qv*sh_Kw[s*TAc + d];
        }
        sh_beta[i] = acc;
    }
    __syncthreads();
    // LayerNorm over (S,T)
    float s0 = 0.f, s1 = 0.f;
    for (int i = tid; i < Sc*Tc; i += 256){ float v = sh_beta[i]; s0 += v; s1 += v*v; }
    r0[tid] = s0; r1[tid] = s1; __syncthreads();
    for (int off = 128; off; off >>= 1){
        if (tid < off){ r0[tid] += r0[tid+off]; r1[tid] += r1[tid+off]; }
        __syncthreads();
    }
    float m = r0[0] / (float)(Sc*Tc);
    float var = r1[0] / (float)(Sc*Tc) - m*m;
    float inv = rsqrtf(var + EPSc);
    __syncthreads();
    for (int i = tid; i < Sc*Tc; i += 256){
        int s = i / Tc, t = i % Tc;
        sh_beta[i] = (sh_beta[i] - m)*inv*lnt_g[s*Tc + t] + lnt_b[s*Tc + t];
    }
    __syncthreads();
    // out1[s,d] = lrelu(sum_t betaN[s,t]*Hc[s,t,d])
    for (int i = tid; i < Sc*32; i += 256){
        int s = i / 32, d = i % 32;
        float acc = 0.f;
        if (d < Ec){
            #pragma unroll 4
            for (int t = 0; t < Tc; t++) acc += sh_beta[s*Tc + t]*h2[(t*Sc + s)*Ec + d];
        } else {
            #pragma unroll 4
            for (int t = 0; t < Tc; t++) acc += sh_beta[s*Tc + t]*sh_pe[t*PEc + d - Ec];
        }
        sh_o1[i] = lrelu(acc);
    }
    __syncthreads();
    // out2[s,k] = lrelu(out1[s,:].Wse[k,:] + bse[k])
    for (int i = tid; i < Sc*16; i += 256){
        int s = i / 16, k = i % 16;
        float acc = bse[k];
        #pragma unroll
        for (int d = 0; d < 32; d++) acc += sh_o1[s*32 + d]*Wse[k*32 + d];
        sh_o2[i] = lrelu(acc);
    }
    __syncthreads();
    // LayerNorm over (S,16) + final write
    s0 = 0.f; s1 = 0.f;
    for (int i = tid; i < Sc*16; i += 256){ float v = sh_o2[i]; s0 += v; s1 += v*v; }
    r0[tid] = s0; r1[tid] = s1; __syncthreads();
    for (int off = 128; off; off >>= 1){
        if (tid < off){ r0[tid] += r0[tid+off]; r1[tid] += r1[tid+off]; }
        __syncthreads();
    }
    float m2 = r0[0] / (float)(Sc*16);
    float v2 = r1[0] / (float)(Sc*16) - m2*m2;
    float inv2 = rsqrtf(v2 + EPSc);
    for (int i = tid; i < Sc*16; i += 256){
        int s = i / 16, k = i % 16;
        out[(b*Sc + s)*OUTc + h*16 + k] = (sh_o2[i] - m2)*inv2*lns_g[s*16 + k] + lns_b[s*16 + k];
    }
}

extern "C" void kernel_launch(void* const* d_in, const int* in_sizes, int n_in,
                              void* d_out, int out_size, void* d_ws, size_t ws_size,
                              hipStream_t stream){
    const float* x     = (const float*)d_in[0];
    const float* times = (const float*)d_in[1];
    const float* mask  = (const float*)d_in[2];
    const float* bn_g  = (const float*)d_in[3];
    const float* bn_b  = (const float*)d_in[4];
    const float* obs   = (const float*)d_in[5];
    const float* attn  = (const float*)d_in[6];
    const float* bidw  = (const float*)d_in[7];
    const float* projW = (const float*)d_in[8];
    const float* projb = (const float*)d_in[9];
    const float* Wq    = (const float*)d_in[10];
    const float* bq    = (const float*)d_in[11];
    const float* Wk    = (const float*)d_in[12];
    const float* bk    = (const float*)d_in[13];
    const float* Ws_   = (const float*)d_in[14];
    const float* bs_   = (const float*)d_in[15];
    const float* lnt_g = (const float*)d_in[16];
    const float* lnt_b = (const float*)d_in[17];
    const float* Wse   = (const float*)d_in[18];
    const float* bse   = (const float*)d_in[19];
    const float* lns_g = (const float*)d_in[20];
    const float* lns_b = (const float*)d_in[21];
    float* ws  = (float*)d_ws;
    float* out = (float*)d_out;

    k_pre<<<64, 256, 0, stream>>>(x, times, bidw, ws);
    k_layer01<<<Bc*Hc_*Tc, 256, 0, stream>>>(x, mask, bn_g, bn_b, obs, attn, projW, projb, ws);
    k_adjsum<<<(Bc*Hc_*Sc*Sc + 255)/256, 256, 0, stream>>>(ws);
    k_prune<<<Bc*Hc_*6, 256, 0, stream>>>(mask, ws);
    k_sim<<<1, 256, 0, stream>>>(ws, out);
    k_layer1mp<<<Bc*Hc_*Tc, 256, 0, stream>>>(ws);
    k_final<<<Bc*Hc_, 256, 0, stream>>>(Wq, bq, Wk, bk, Ws_, bs_, lnt_g, lnt_b,
                                        Wse, bse, lns_g, lns_b, ws, out);
}

// Round 3
// 235.699 us; speedup vs baseline: 1.9544x; 1.2120x over previous
//
#include <hip/hip_runtime.h>
#include <math.h>

#define Bc 8
#define Tc 60
#define Sc 36
#define Hc_ 4
#define Ec 16
#define PEc 16
#define ADc 12
#define TAc 10
#define OUTc 64
#define KEEP 648
#define EPSc 1e-5f

// workspace layout (float offsets)
#define WS_MU     0
#define WS_VAR    64
#define WS_PE     128                      // B*T*PE = 7680
#define WS_BIDIR  7808                     // L*H*S*S = 10368
#define WS_H2     18176                    // B*H*T*S*E = 1105920  (layer-1 output)
#define WS_H1     1124096                  // 1105920              (layer-0 output)
#define WS_ALPHA  2230016                  // B*H*T*S*S = 2488320
#define WS_ADJSUM 4718336                  // B*H*S*S = 41472
#define WS_ADJ    4759808                  // 41472
// final-chain buffers overlay the (dead-by-then) ALPHA region:
#define WS_BETA   WS_ALPHA                 // B*H*S*T = 69120
#define WS_PART   (WS_ALPHA + 69120)       // B*H*S*2 = 2304
#define WS_OUT2   (WS_ALPHA + 71424)       // B*H*S*16 = 18432
#define WS_PART2  (WS_ALPHA + 89856)       // B*H*S*2 = 2304

__device__ __forceinline__ float lrelu(float v){ return v >= 0.f ? v : 0.01f*v; }

// ------------- kernel 1: BN stats per t + positional encoding + bidir -------------
__global__ __launch_bounds__(256) void k_pre(const float* __restrict__ x,
                      const float* __restrict__ times,
                      const float* __restrict__ bidw,
                      float* __restrict__ ws){
    int tid = threadIdx.x;
    __shared__ float r0[256], r1[256];
    if (blockIdx.x < Tc){
        int t = blockIdx.x;
        float s0 = 0.f, s1 = 0.f;
        for (int i = tid; i < Bc*Sc; i += 256){
            int b = i / Sc, s = i % Sc;
            float v = x[(b*Tc + t)*Sc + s];
            s0 += v; s1 += v*v;
        }
        r0[tid] = s0; r1[tid] = s1; __syncthreads();
        for (int off = 128; off; off >>= 1){
            if (tid < off){ r0[tid] += r0[tid+off]; r1[tid] += r1[tid+off]; }
            __syncthreads();
        }
        if (tid == 0){
            float mu = r0[0] / (float)(Bc*Sc);
            ws[WS_MU + t] = mu;
            ws[WS_VAR + t] = r1[0] / (float)(Bc*Sc) - mu*mu;
        }
    }
    int gid = blockIdx.x * 256 + tid;
    if (gid < Bc*Tc*8){
        int b = gid / (Tc*8); int r = gid % (Tc*8); int t = r / 8; int j = r % 8;
        float div = expf(-(float)j * 1.15129254649702284f);   // log(10000)/8
        float ang = times[b*Tc + t] * div;
        float* pe = ws + WS_PE + (b*Tc + t)*PEc;
        pe[2*j]   = sinf(ang);
        pe[2*j+1] = cosf(ang);
    }
    if (gid < 2*Hc_*Sc*Sc){
        int r = gid; int lay = r / (Hc_*Sc*Sc); r %= (Hc_*Sc*Sc);
        int h = r / (Sc*Sc); int sj = r % (Sc*Sc); int s = sj / Sc; int j = sj % Sc;
        const float* ps = bidw + ((lay*Hc_ + h)*Sc + s)*ADc;
        const float* pj = bidw + ((lay*Hc_ + h)*Sc + j)*ADc;
        float acc = 0.f;
        #pragma unroll
        for (int d = 0; d < ADc; d++) acc += ps[d]*pj[d];
        ws[WS_BIDIR + gid] = lrelu(acc);
    }
}

// ---- kernel 2: fused BN-apply + embed + layer0 (alpha0,w0,mp -> h1) + alpha1 ----
__global__ __launch_bounds__(256) void k_layer01(const float* __restrict__ x,
                          const float* __restrict__ mask,
                          const float* __restrict__ bn_g,
                          const float* __restrict__ bn_b,
                          const float* __restrict__ obs_w,
                          const float* __restrict__ attn,
                          const float* __restrict__ projW,
                          const float* __restrict__ projb,
                          float* __restrict__ ws){
    int idx = blockIdx.x;                 // (b*H + h)*T + t
    int t = idx % Tc; int bh = idx / Tc; int h = bh % Hc_; int b = bh / Hc_;
    int tid = threadIdx.x;
    __shared__ float sh_h[Sc*Ec];         // h0
    __shared__ float sh_h1[Sc*Ec];
    __shared__ float sh_pe[PEc];
    __shared__ float sh_at0[Sc*ADc];
    __shared__ float sh_at1[Sc*ADc];
    __shared__ float sh_hp[Sc*28];
    __shared__ float sh_w[Sc*Sc];
    __shared__ float sh_xn[Sc];
    __shared__ float sh_m[Sc];
    if (tid < Sc){
        float mu = ws[WS_MU + t], var = ws[WS_VAR + t];
        float xv = x[(b*Tc + t)*Sc + tid];
        sh_xn[tid] = (xv - mu) * rsqrtf(var + EPSc) * bn_g[t] + bn_b[t];
        sh_m[tid]  = mask[(b*Tc + t)*Sc + tid];
    }
    for (int i = tid; i < PEc; i += 256) sh_pe[i] = ws[WS_PE + (b*Tc + t)*PEc + i];
    for (int i = tid; i < Sc*ADc; i += 256){
        sh_at0[i] = attn[h*Sc*ADc + i];
        sh_at1[i] = attn[(Hc_ + h)*Sc*ADc + i];
    }
    __syncthreads();
    for (int i = tid; i < Sc*Ec; i += 256){
        int s = i / Ec, e = i % Ec;
        sh_h[i] = lrelu(sh_xn[s]*obs_w[s*64 + h*Ec + e]) * sh_m[s];
    }
    __syncthreads();
    // hp0 = h0 @ projW.T + projb
    for (int i = tid; i < Sc*28; i += 256){
        int s = i / 28, d = i % 28;
        float acc = projb[d];
        const float* w = projW + d*Ec;
        const float* hh = sh_h + s*Ec;
        #pragma unroll
        for (int e = 0; e < Ec; e++) acc += hh[e]*w[e];
        sh_hp[i] = acc;
    }
    __syncthreads();
    const float* bid0 = ws + WS_BIDIR + h*Sc*Sc;
    for (int i = tid; i < Sc*Sc; i += 256){
        int s = i / Sc, j = i % Sc;
        const float* hp = sh_hp + s*28;
        float acc = 0.f;
        #pragma unroll
        for (int d = 0; d < ADc; d++) acc += hp[d]*sh_at0[j*ADc + d];
        #pragma unroll
        for (int d = 0; d < PEc; d++) acc += hp[ADc + d]*sh_pe[d];
        sh_w[i] = lrelu(bid0[i]*lrelu(acc));     // adj == 1 at layer 0
    }
    __syncthreads();
    float* h1g = ws + WS_H1 + (size_t)idx*Sc*Ec;
    for (int i = tid; i < Sc*Ec; i += 256){
        int s = i / Ec, e = i % Ec;
        float acc = 0.f;
        #pragma unroll 6
        for (int j = 0; j < Sc; j++) acc += lrelu(sh_h[j*Ec + e]*sh_w[s*Sc + j]);
        float v = lrelu(acc);
        sh_h1[i] = v;
        h1g[i] = v;
    }
    __syncthreads();
    // hp1 = h1 @ projW.T + projb  (reuse sh_hp)
    for (int i = tid; i < Sc*28; i += 256){
        int s = i / 28, d = i % 28;
        float acc = projb[d];
        const float* w = projW + d*Ec;
        const float* hh = sh_h1 + s*Ec;
        #pragma unroll
        for (int e = 0; e < Ec; e++) acc += hh[e]*w[e];
        sh_hp[i] = acc;
    }
    __syncthreads();
    float* adst = ws + WS_ALPHA + (size_t)idx*Sc*Sc;
    for (int i = tid; i < Sc*Sc; i += 256){
        int s = i / Sc, j = i % Sc;
        const float* hp = sh_hp + s*28;
        float acc = 0.f;
        #pragma unroll
        for (int d = 0; d < ADc; d++) acc += hp[d]*sh_at1[j*ADc + d];
        #pragma unroll
        for (int d = 0; d < PEc; d++) acc += hp[ADc + d]*sh_pe[d];
        adst[i] = lrelu(acc);
    }
}

// ---------------- kernel 3: adj column-sum over t (deterministic) ----------------
__global__ __launch_bounds__(256) void k_adjsum(float* __restrict__ ws){
    int gid = blockIdx.x * 256 + threadIdx.x;
    if (gid >= Bc*Hc_*Sc*Sc) return;
    int bh = gid / (Sc*Sc); int sj = gid % (Sc*Sc);
    const float* a = ws + WS_ALPHA + (size_t)bh*Tc*Sc*Sc + sj;
    float acc = 0.f;
    #pragma unroll 4
    for (int t = 0; t < Tc; t++) acc += a[(size_t)t*Sc*Sc];
    ws[WS_ADJSUM + gid] = acc;
}

// -------- kernel 4: adj = lrelu(sum/cnt); prune by stable rank (1 elem/thread) --------
__global__ __launch_bounds__(256) void k_prune(const float* __restrict__ mask, float* __restrict__ ws){
    int bh = blockIdx.x / 6; int chunk = blockIdx.x % 6;
    int b = bh / Hc_;
    int tid = threadIdx.x;
    __shared__ float sh_v[Sc*Sc];
    __shared__ float sh_cnt[Sc];
    if (tid < Sc){
        float c = 0.f;
        #pragma unroll 4
        for (int t = 0; t < Tc; t++) c += mask[(b*Tc + t)*Sc + tid];
        sh_cnt[tid] = c;
    }
    __syncthreads();
    for (int i = tid; i < Sc*Sc; i += 256){
        int s = i / Sc;
        sh_v[i] = lrelu(ws[WS_ADJSUM + bh*Sc*Sc + i] / sh_cnt[s]);
    }
    __syncthreads();
    int i = chunk*216 + tid;         // 6*216 = 1296
    if (tid < 216){
        float v = sh_v[i];
        int rank = 0;
        #pragma unroll 8
        for (int k = 0; k < Sc*Sc; k++){
            float u = sh_v[k];
            rank += (u < v) || (u == v && k < i);   // stable-sort rank
        }
        ws[WS_ADJ + bh*Sc*Sc + i] = (rank >= KEEP) ? v : 0.f;
    }
}

// ---------------- kernel 5: pair_sim(adj) -> d_out[18432] ----------------
__global__ __launch_bounds__(256) void k_sim(const float* __restrict__ ws, float* __restrict__ out){
    int tid = threadIdx.x;
    float sq = 0.f, t2 = 0.f;
    for (int i = tid; i < Hc_*Sc*Sc; i += 256){
        float tot = 0.f;
        #pragma unroll
        for (int b = 0; b < Bc; b++){
            float v = ws[WS_ADJ + b*Hc_*Sc*Sc + i];
            sq += v*v; tot += v;
        }
        t2 += tot*tot;
    }
    __shared__ float r0[256], r1[256];
    r0[tid] = sq; r1[tid] = t2; __syncthreads();
    for (int off = 128; off; off >>= 1){
        if (tid < off){ r0[tid] += r0[tid+off]; r1[tid] += r1[tid+off]; }
        __syncthreads();
    }
    if (tid == 0)
        out[Bc*Sc*OUTc] = ((float)Bc*r0[0] - r1[0]) / 49.f / 1296.f;
}

// ---------------- kernel 6: layer 1 message passing ----------------
__global__ __launch_bounds__(256) void k_layer1mp(float* __restrict__ ws){
    int idx = blockIdx.x;
    int bh = idx / Tc; int h = bh % Hc_;
    int tid = threadIdx.x;
    __shared__ float sh_h[Sc*Ec];
    __shared__ float sh_w[Sc*Sc];
    const float* hsrc = ws + WS_H1 + (size_t)idx*Sc*Ec;
    float*       hdst = ws + WS_H2 + (size_t)idx*Sc*Ec;
    const float* al  = ws + WS_ALPHA + (size_t)idx*Sc*Sc;
    const float* adj = ws + WS_ADJ + bh*Sc*Sc;
    const float* bid = ws + WS_BIDIR + (Hc_ + h)*Sc*Sc;
    for (int i = tid; i < Sc*Ec; i += 256) sh_h[i] = hsrc[i];
    for (int i = tid; i < Sc*Sc; i += 256) sh_w[i] = lrelu(bid[i]*al[i]*adj[i]);
    __syncthreads();
    for (int i = tid; i < Sc*Ec; i += 256){
        int s = i / Ec, e = i % Ec;
        float acc = 0.f;
        #pragma unroll 6
        for (int j = 0; j < Sc; j++) acc += lrelu(sh_h[j*Ec + e]*sh_w[s*Sc + j]);
        hdst[i] = lrelu(acc);
    }
}

// ------- kernel 7a: per-(b,h,s) temporal attention: beta + LN1 partials -------
__global__ __launch_bounds__(64) void kF1(const float* __restrict__ Wq, const float* __restrict__ bq,
                   const float* __restrict__ Wk, const float* __restrict__ bk,
                   const float* __restrict__ Ws_, const float* __restrict__ bs_,
                   float* __restrict__ ws){
    int idx = blockIdx.x;                  // bh*Sc + s
    int s = idx % Sc; int bh = idx / Sc; int b = bh / Hc_;
    int tid = threadIdx.x;
    __shared__ float sh_Hc[Tc*33];         // row-pad 33: bank (t+q)%32
    __shared__ float sh_K[Tc*11];
    __shared__ float sh_Wq[TAc*32], sh_Wk[TAc*32];
    __shared__ float sh_bq[TAc], sh_bk[TAc];
    __shared__ float sh_ws[Tc];
    __shared__ float sh_Kw[TAc];
    const float* h2 = ws + WS_H2 + (size_t)bh*Tc*Sc*Ec + s*Ec;   // + t*576
    const float* pe = ws + WS_PE + b*Tc*PEc;
    // stage Hc rows: [t][0..15] = h2, [t][16..31] = pe
    for (int i = tid; i < Tc*Ec; i += 64){
        int t = i / Ec, e = i % Ec;
        sh_Hc[t*33 + e]      = h2[t*Sc*Ec + e];
        sh_Hc[t*33 + Ec + e] = pe[t*PEc + e];
    }
    for (int i = tid; i < TAc*32; i += 64){ sh_Wq[i] = Wq[i]; sh_Wk[i] = Wk[i]; }
    if (tid < TAc){ sh_bq[tid] = bq[tid]; sh_bk[tid] = bk[tid]; }
    if (tid < Tc) sh_ws[tid] = Ws_[tid];
    __syncthreads();
    // K[t,d]
    for (int i = tid; i < Tc*TAc; i += 64){
        int t = i / TAc, d = i % TAc;
        const float* wk = sh_Wk + d*32;
        const float* hc = sh_Hc + t*33;
        float acc = sh_bk[d];
        #pragma unroll
        for (int q = 0; q < 32; q++) acc += hc[q]*wk[q];
        sh_K[t*11 + d] = acc;
    }
    __syncthreads();
    // Kw[d] = sum_t K[t,d]*Ws[t]
    if (tid < TAc){
        float acc = 0.f;
        #pragma unroll 4
        for (int t = 0; t < Tc; t++) acc += sh_K[t*11 + tid]*sh_ws[t];
        sh_Kw[tid] = acc;
    }
    __syncthreads();
    // beta[t] = sum_d (Q[t,d]) * Kw[d] + bs
    float bv = 0.f;
    float bsv = bs_[0];
    if (tid < Tc){
        const float* hc = sh_Hc + tid*33;
        float acc = bsv;
        #pragma unroll
        for (int d = 0; d < TAc; d++){
            const float* wq = sh_Wq + d*32;
            float qv = sh_bq[d];
            #pragma unroll
            for (int q = 0; q < 32; q++) qv += hc[q]*wq[q];
            acc += qv*sh_Kw[d];
        }
        bv = acc;
        ws[WS_BETA + idx*Tc + tid] = acc;
    }
    // LN1 partial sums over this block's 60 betas
    float p0 = (tid < Tc) ? bv : 0.f;
    float p1 = p0*bv;
    #pragma unroll
    for (int off = 32; off; off >>= 1){
        p0 += __shfl_down(p0, off, 64);
        p1 += __shfl_down(p1, off, 64);
    }
    if (tid == 0){
        ws[WS_PART + idx*2]     = p0;
        ws[WS_PART + idx*2 + 1] = p1;
    }
}

// ------- kernel 7b: per-(b,h,s) LN1-normalize + out1 + out2 + LN2 partials -------
__global__ __launch_bounds__(64) void kF2(const float* __restrict__ lnt_g, const float* __restrict__ lnt_b,
                   const float* __restrict__ Wse, const float* __restrict__ bse,
                   float* __restrict__ ws){
    int idx = blockIdx.x;
    int s = idx % Sc; int bh = idx / Sc; int b = bh / Hc_;
    int tid = threadIdx.x;
    __shared__ float sh_Hc[Tc*33];
    __shared__ float sh_beta[Tc];
    __shared__ float sh_o1[32];
    __shared__ float sh_mi[2];
    // LN1 stats: redundant reduce of 36 partials
    float p0 = 0.f, p1 = 0.f;
    if (tid < Sc){
        p0 = ws[WS_PART + (bh*Sc + tid)*2];
        p1 = ws[WS_PART + (bh*Sc + tid)*2 + 1];
    }
    #pragma unroll
    for (int off = 32; off; off >>= 1){
        p0 += __shfl_down(p0, off, 64);
        p1 += __shfl_down(p1, off, 64);
    }
    if (tid == 0){
        float m = p0 / (float)(Sc*Tc);
        sh_mi[0] = m;
        sh_mi[1] = rsqrtf(p1 / (float)(Sc*Tc) - m*m + EPSc);
    }
    const float* h2 = ws + WS_H2 + (size_t)bh*Tc*Sc*Ec + s*Ec;
    const float* pe = ws + WS_PE + b*Tc*PEc;
    for (int i = tid; i < Tc*Ec; i += 64){
        int t = i / Ec, e = i % Ec;
        sh_Hc[t*33 + e]      = h2[t*Sc*Ec + e];
        sh_Hc[t*33 + Ec + e] = pe[t*PEc + e];
    }
    __syncthreads();
    float m = sh_mi[0], inv = sh_mi[1];
    if (tid < Tc){
        float bvv = ws[WS_BETA + idx*Tc + tid];
        sh_beta[tid] = (bvv - m)*inv*lnt_g[s*Tc + tid] + lnt_b[s*Tc + tid];
    }
    __syncthreads();
    // out1[d] = lrelu(sum_t betaN[t]*Hc[t,d])
    if (tid < 32){
        float acc = 0.f;
        #pragma unroll 4
        for (int t = 0; t < Tc; t++) acc += sh_beta[t]*sh_Hc[t*33 + tid];
        sh_o1[tid] = lrelu(acc);
    }
    __syncthreads();
    // out2[k] = lrelu(out1 . Wse[k,:] + bse[k]); LN2 partials
    float v = 0.f;
    if (tid < 16){
        float acc = bse[tid];
        const float* w = Wse + tid*32;
        #pragma unroll
        for (int d = 0; d < 32; d++) acc += sh_o1[d]*w[d];
        v = lrelu(acc);
        ws[WS_OUT2 + idx*16 + tid] = v;
    }
    float q0 = v, q1 = v*v;
    #pragma unroll
    for (int off = 32; off; off >>= 1){
        q0 += __shfl_down(q0, off, 64);
        q1 += __shfl_down(q1, off, 64);
    }
    if (tid == 0){
        ws[WS_PART2 + idx*2]     = q0;
        ws[WS_PART2 + idx*2 + 1] = q1;
    }
}

// ------- kernel 7c: per-(b,h) LN2 + final write -------
__global__ __launch_bounds__(64) void kF3(const float* __restrict__ lns_g, const float* __restrict__ lns_b,
                   const float* __restrict__ ws, float* __restrict__ out){
    int bh = blockIdx.x; int h = bh % Hc_; int b = bh / Hc_;
    int tid = threadIdx.x;
    __shared__ float sh_mi[2];
    float p0 = 0.f, p1 = 0.f;
    if (tid < Sc){
        p0 = ws[WS_PART2 + (bh*Sc + tid)*2];
        p1 = ws[WS_PART2 + (bh*Sc + tid)*2 + 1];
    }
    #pragma unroll
    for (int off = 32; off; off >>= 1){
        p0 += __shfl_down(p0, off, 64);
        p1 += __shfl_down(p1, off, 64);
    }
    if (tid == 0){
        float m = p0 / (float)(Sc*16);
        sh_mi[0] = m;
        sh_mi[1] = rsqrtf(p1 / (float)(Sc*16) - m*m + EPSc);
    }
    __syncthreads();
    float m2 = sh_mi[0], inv2 = sh_mi[1];
    for (int i = tid; i < Sc*16; i += 64){
        int s = i / 16, k = i % 16;
        float v = ws[WS_OUT2 + bh*Sc*16 + i];
        out[(b*Sc + s)*OUTc + h*16 + k] = (v - m2)*inv2*lns_g[i] + lns_b[i];
    }
}

extern "C" void kernel_launch(void* const* d_in, const int* in_sizes, int n_in,
                              void* d_out, int out_size, void* d_ws, size_t ws_size,
                              hipStream_t stream){
    const float* x     = (const float*)d_in[0];
    const float* times = (const float*)d_in[1];
    const float* mask  = (const float*)d_in[2];
    const float* bn_g  = (const float*)d_in[3];
    const float* bn_b  = (const float*)d_in[4];
    const float* obs   = (const float*)d_in[5];
    const float* attn  = (const float*)d_in[6];
    const float* bidw  = (const float*)d_in[7];
    const float* projW = (const float*)d_in[8];
    const float* projb = (const float*)d_in[9];
    const float* Wq    = (const float*)d_in[10];
    const float* bq    = (const float*)d_in[11];
    const float* Wk    = (const float*)d_in[12];
    const float* bk    = (const float*)d_in[13];
    const float* Ws_   = (const float*)d_in[14];
    const float* bs_   = (const float*)d_in[15];
    const float* lnt_g = (const float*)d_in[16];
    const float* lnt_b = (const float*)d_in[17];
    const float* Wse   = (const float*)d_in[18];
    const float* bse   = (const float*)d_in[19];
    const float* lns_g = (const float*)d_in[20];
    const float* lns_b = (const float*)d_in[21];
    float* ws  = (float*)d_ws;
    float* out = (float*)d_out;

    k_pre<<<64, 256, 0, stream>>>(x, times, bidw, ws);
    k_layer01<<<Bc*Hc_*Tc, 256, 0, stream>>>(x, mask, bn_g, bn_b, obs, attn, projW, projb, ws);
    k_adjsum<<<(Bc*Hc_*Sc*Sc + 255)/256, 256, 0, stream>>>(ws);
    k_prune<<<Bc*Hc_*6, 256, 0, stream>>>(mask, ws);
    k_sim<<<1, 256, 0, stream>>>(ws, out);
    k_layer1mp<<<Bc*Hc_*Tc, 256, 0, stream>>>(ws);
    kF1<<<Bc*Hc_*Sc, 64, 0, stream>>>(Wq, bq, Wk, bk, Ws_, bs_, ws);
    kF2<<<Bc*Hc_*Sc, 64, 0, stream>>>(lnt_g, lnt_b, Wse, bse, ws);
    kF3<<<Bc*Hc_, 64, 0, stream>>>(lns_g, lns_b, ws, out);
}